// Round 1
// baseline (1520.591 us; speedup 1.0000x reference)
//
#include <hip/hip_runtime.h>

// GraphSAGE 2-layer, mean aggregation, d_in = d_h = 32.
// out = relu( (segsum(x[src],dst)/max(deg,1)) @ Wl + b + x @ Wr ), twice.

constexpr int D = 32;

// One thread per edge: deg[dst] += 1
__global__ void deg_kernel(const int* __restrict__ dst, float* __restrict__ deg, int E) {
    int e = blockIdx.x * blockDim.x + threadIdx.x;
    if (e < E) atomicAdd(&deg[dst[e]], 1.0f);
}

// 8 threads per edge, each moves a float4 (node row = 32 fp32 = 128B = 1 cacheline)
__global__ void scatter_kernel(const float* __restrict__ xin,
                               const int* __restrict__ src,
                               const int* __restrict__ dst,
                               float* __restrict__ agg, int E) {
    long long idx = (long long)blockIdx.x * blockDim.x + threadIdx.x;
    int e = (int)(idx >> 3);
    if (e >= E) return;
    int f = ((int)idx & 7) * 4;
    int s = src[e], d = dst[e];
    const float4 v = *reinterpret_cast<const float4*>(xin + (long long)s * D + f);
    float* a = agg + (long long)d * D + f;
    atomicAdd(a + 0, v.x);
    atomicAdd(a + 1, v.y);
    atomicAdd(a + 2, v.z);
    atomicAdd(a + 3, v.w);
}

// Block of 256 handles 8 nodes; weights (32x32 x2) staged in LDS.
// out[n][j] = relu( (1/max(deg,1)) * sum_k agg[n][k]*Wl[k][j] + b[j] + sum_k x[n][k]*Wr[k][j] )
__global__ void combine_kernel(const float* __restrict__ agg,
                               const float* __restrict__ deg,
                               const float* __restrict__ xin,
                               const float* __restrict__ Wl,
                               const float* __restrict__ Wr,
                               const float* __restrict__ b,
                               float* __restrict__ out, int n_nodes) {
    __shared__ float sWl[D * D];
    __shared__ float sWr[D * D];
    __shared__ float sAgg[8 * D];
    __shared__ float sX[8 * D];
    int t = threadIdx.x;  // 256 threads
    // stage weights
    sWl[t] = Wl[t];
    sWl[t + 256] = Wl[t + 256];
    sWl[t + 512] = Wl[t + 512];
    sWl[t + 768] = Wl[t + 768];
    sWr[t] = Wr[t];
    sWr[t + 256] = Wr[t + 256];
    sWr[t + 512] = Wr[t + 512];
    sWr[t + 768] = Wr[t + 768];
    int node_base = blockIdx.x * 8;
    long long gidx = (long long)node_base * D + t;
    int my_node_for_load = node_base + t / D;
    if (my_node_for_load < n_nodes) {
        sAgg[t] = agg[gidx];
        sX[t] = xin[gidx];
    } else {
        sAgg[t] = 0.f;
        sX[t] = 0.f;
    }
    __syncthreads();
    int ln = t >> 5;      // local node 0..7
    int j = t & 31;       // output feature
    int n = node_base + ln;
    if (n >= n_nodes) return;
    float rdeg = 1.0f / fmaxf(deg[n], 1.0f);
    float accA = 0.f, accX = 0.f;
    const float* ar = sAgg + ln * D;
    const float* xr = sX + ln * D;
#pragma unroll
    for (int k = 0; k < D; ++k) {
        accA += ar[k] * sWl[k * D + j];
        accX += xr[k] * sWr[k * D + j];
    }
    float r = accA * rdeg + b[j] + accX;
    out[(long long)n * D + j] = fmaxf(r, 0.0f);
}

extern "C" void kernel_launch(void* const* d_in, const int* in_sizes, int n_in,
                              void* d_out, int out_size, void* d_ws, size_t ws_size,
                              hipStream_t stream) {
    const float* x   = (const float*)d_in[0];
    const int*   ei  = (const int*)d_in[1];
    const float* W1l = (const float*)d_in[2];
    const float* W1r = (const float*)d_in[3];
    const float* b1  = (const float*)d_in[4];
    const float* W2l = (const float*)d_in[5];
    const float* W2r = (const float*)d_in[6];
    const float* b2  = (const float*)d_in[7];
    float* out = (float*)d_out;

    const int n_nodes = in_sizes[0] / D;
    const int E = in_sizes[1] / 2;
    const int* src = ei;
    const int* dst = ei + E;

    // workspace layout: agg [n*D] | deg [n] | h [n*D]
    float* agg = (float*)d_ws;
    float* deg = agg + (size_t)n_nodes * D;
    float* h   = deg + (size_t)n_nodes;

    // zero agg + deg
    hipMemsetAsync(d_ws, 0, ((size_t)n_nodes * D + n_nodes) * sizeof(float), stream);

    // degree (shared by both layers)
    deg_kernel<<<(E + 255) / 256, 256, 0, stream>>>(dst, deg, E);

    const long long scatter_threads = (long long)E * 8;
    const int scatter_blocks = (int)((scatter_threads + 255) / 256);
    const int combine_blocks = (n_nodes + 7) / 8;

    // layer 1
    scatter_kernel<<<scatter_blocks, 256, 0, stream>>>(x, src, dst, agg, E);
    combine_kernel<<<combine_blocks, 256, 0, stream>>>(agg, deg, x, W1l, W1r, b1, h, n_nodes);

    // layer 2
    hipMemsetAsync(agg, 0, (size_t)n_nodes * D * sizeof(float), stream);
    scatter_kernel<<<scatter_blocks, 256, 0, stream>>>(h, src, dst, agg, E);
    combine_kernel<<<combine_blocks, 256, 0, stream>>>(agg, deg, h, W2l, W2r, b2, out, n_nodes);
}

// Round 2
// 472.258 us; speedup vs baseline: 3.2198x; 3.2198x over previous
//
#include <hip/hip_runtime.h>

// GraphSAGE 2-layer, mean aggregation, d = 32, via on-device CSR build
// (counting sort of edges by dst) + fused gather/normalize/GEMM/relu layers.

constexpr int D = 32;

// ---- CSR build ----

__global__ void hist_kernel(const int* __restrict__ dst, int* __restrict__ cnt, int E) {
    int e = blockIdx.x * blockDim.x + threadIdx.x;
    if (e < E) atomicAdd(&cnt[dst[e]], 1);
}

// Exclusive scan, phase A: per-block (1024 elems) exclusive scan + block total.
__global__ void scan_block(const int* __restrict__ cnt, int* __restrict__ row_ptr,
                           int* __restrict__ partials, int n) {
    __shared__ int sSums[256];
    int t = threadIdx.x;
    int idx = blockIdx.x * 1024 + t * 4;
    int v0 = 0, v1 = 0, v2 = 0, v3 = 0;
    if (idx + 3 < n) {
        int4 v = *reinterpret_cast<const int4*>(cnt + idx);
        v0 = v.x; v1 = v.y; v2 = v.z; v3 = v.w;
    } else {
        if (idx + 0 < n) v0 = cnt[idx + 0];
        if (idx + 1 < n) v1 = cnt[idx + 1];
        if (idx + 2 < n) v2 = cnt[idx + 2];
        if (idx + 3 < n) v3 = cnt[idx + 3];
    }
    int s0 = v0, s1 = s0 + v1, s2 = s1 + v2, s3 = s2 + v3;
    sSums[t] = s3;
    __syncthreads();
    for (int off = 1; off < 256; off <<= 1) {
        int val = (t >= off) ? sSums[t - off] : 0;
        __syncthreads();
        sSums[t] += val;
        __syncthreads();
    }
    int excl = sSums[t] - s3;
    if (idx + 0 < n) row_ptr[idx + 0] = excl;
    if (idx + 1 < n) row_ptr[idx + 1] = excl + s0;
    if (idx + 2 < n) row_ptr[idx + 2] = excl + s1;
    if (idx + 3 < n) row_ptr[idx + 3] = excl + s2;
    if (t == 255) partials[blockIdx.x] = sSums[255];
}

// Phase B: single-block exclusive scan of block totals (nb <= 128).
__global__ void scan_partials(int* __restrict__ partials, int nb) {
    __shared__ int s[128];
    int t = threadIdx.x;
    int v = (t < nb) ? partials[t] : 0;
    s[t] = v;
    __syncthreads();
    for (int off = 1; off < 128; off <<= 1) {
        int val = (t >= off) ? s[t - off] : 0;
        __syncthreads();
        s[t] += val;
        __syncthreads();
    }
    if (t < nb) partials[t] = s[t] - v;
}

// Phase C: add block bases; duplicate into `next` (fill cursors); cap row_ptr[n]=E.
__global__ void scan_add(int* __restrict__ row_ptr, int* __restrict__ next,
                         const int* __restrict__ partials, int n, int E) {
    int i = blockIdx.x * blockDim.x + threadIdx.x;
    if (i < n) {
        int v = row_ptr[i] + partials[i >> 10];
        row_ptr[i] = v;
        next[i] = v;
    }
    if (i == 0) row_ptr[n] = E;
}

// Bucket fill: perm_src[slot in dst's bucket] = src.
__global__ void fill_kernel(const int* __restrict__ src, const int* __restrict__ dst,
                            int* __restrict__ next, int* __restrict__ perm_src, int E) {
    int e = blockIdx.x * blockDim.x + threadIdx.x;
    if (e < E) {
        int p = atomicAdd(&next[dst[e]], 1);
        perm_src[p] = src[e];
    }
}

// ---- Fused SAGE layer ----
// Block = 256 threads = 8 nodes x 32 lanes (lane j = feature j).
// Per node: acc_j = sum over edges of xin[sid][j]; agg = acc/max(deg,1);
// out[n][j] = relu( sum_k agg[k]*Wl[k][j] + b[j] + sum_k xin[n][k]*Wr[k][j] ).
__global__ void sage_layer(const float* __restrict__ xin,
                           const int* __restrict__ row_ptr,
                           const int* __restrict__ perm_src,
                           const float* __restrict__ Wl,
                           const float* __restrict__ Wr,
                           const float* __restrict__ b,
                           float* __restrict__ out, int n_nodes) {
    __shared__ float sWl[D * D];
    __shared__ float sWr[D * D];
    __shared__ float sAgg[8 * D];
    __shared__ float sX[8 * D];
    int t = threadIdx.x;
#pragma unroll
    for (int i = 0; i < 4; ++i) {
        sWl[t + i * 256] = Wl[t + i * 256];
        sWr[t + i * 256] = Wr[t + i * 256];
    }
    int ln = t >> 5;
    int j = t & 31;
    int n = blockIdx.x * 8 + ln;
    float acc = 0.f, xv = 0.f, rdeg = 1.f;
    if (n < n_nodes) {
        int e0 = row_ptr[n], e1 = row_ptr[n + 1];
        for (int e = e0; e < e1; ++e) {
            int sid = perm_src[e];                  // broadcast within group
            acc += xin[sid * D + j];                // 128B cacheline per group
        }
        rdeg = 1.f / fmaxf((float)(e1 - e0), 1.f);
        xv = xin[n * D + j];
    }
    sAgg[ln * D + j] = acc * rdeg;
    sX[ln * D + j] = xv;
    __syncthreads();
    if (n >= n_nodes) return;
    float accA = 0.f, accX = 0.f;
    const float* ar = sAgg + ln * D;
    const float* xr = sX + ln * D;
#pragma unroll
    for (int k = 0; k < D; ++k) {
        accA += ar[k] * sWl[k * D + j];
        accX += xr[k] * sWr[k * D + j];
    }
    out[n * D + j] = fmaxf(accA + b[j] + accX, 0.f);
}

extern "C" void kernel_launch(void* const* d_in, const int* in_sizes, int n_in,
                              void* d_out, int out_size, void* d_ws, size_t ws_size,
                              hipStream_t stream) {
    const float* x   = (const float*)d_in[0];
    const int*   ei  = (const int*)d_in[1];
    const float* W1l = (const float*)d_in[2];
    const float* W1r = (const float*)d_in[3];
    const float* b1  = (const float*)d_in[4];
    const float* W2l = (const float*)d_in[5];
    const float* W2r = (const float*)d_in[6];
    const float* b2  = (const float*)d_in[7];
    float* out = (float*)d_out;

    const int n = in_sizes[0] / D;
    const int E = in_sizes[1] / 2;
    const int* src = ei;
    const int* dst = ei + E;

    // ws layout: cnt[n] | row_ptr[n+1] | next[n] | partials[128] | perm_src[E] | h[n*D]
    int* cnt      = (int*)d_ws;
    int* row_ptr  = cnt + n;
    int* next     = row_ptr + (n + 1);
    int* partials = next + n;
    int* perm_src = partials + 128;
    float* h      = (float*)(perm_src + E);

    hipMemsetAsync(cnt, 0, (size_t)n * sizeof(int), stream);

    const int nb = (n + 1023) / 1024;   // scan blocks (98 for n=100000)
    hist_kernel<<<(E + 255) / 256, 256, 0, stream>>>(dst, cnt, E);
    scan_block<<<nb, 256, 0, stream>>>(cnt, row_ptr, partials, n);
    scan_partials<<<1, 128, 0, stream>>>(partials, nb);
    scan_add<<<(n + 255) / 256, 256, 0, stream>>>(row_ptr, next, partials, n, E);
    fill_kernel<<<(E + 255) / 256, 256, 0, stream>>>(src, dst, next, perm_src, E);

    const int layer_blocks = (n + 7) / 8;
    sage_layer<<<layer_blocks, 256, 0, stream>>>(x, row_ptr, perm_src, W1l, W1r, b1, h, n);
    sage_layer<<<layer_blocks, 256, 0, stream>>>(h, row_ptr, perm_src, W2l, W2r, b2, out, n);
}